// Round 3
// baseline (592.275 us; speedup 1.0000x reference)
//
#include <hip/hip_runtime.h>

#define BS 512
#define SL 1024
#define NC 64

// ---------------------------------------------------------------------------
// Cross-lane primitives (wave64). All loop-time ops are VALU-rate.
// ---------------------------------------------------------------------------
template <int CTRL>
__device__ __forceinline__ float dppf(float x) {
    return __int_as_float(__builtin_amdgcn_mov_dpp(__float_as_int(x), CTRL, 0xF, 0xF, true));
}
__device__ __forceinline__ float rflf(float x) {
    return __int_as_float(__builtin_amdgcn_readfirstlane(__float_as_int(x)));
}

// Split x into the two 32-halves: one output holds data of lanes 0-31
// replicated to both halves, the other lanes 32-63 (assignment convention
// resolved at runtime by the probe below).
__device__ __forceinline__ void halfswap32(float x, float& r0, float& r1) {
#if __has_builtin(__builtin_amdgcn_permlane32_swap)
    auto r = __builtin_amdgcn_permlane32_swap(__float_as_int(x), __float_as_int(x), false, false);
    r0 = __int_as_float(r[0]); r1 = __int_as_float(r[1]);
#else
    float w = __shfl_xor(x, 32, 64);
    bool up = (threadIdx.x & 32) != 0;
    r0 = up ? w : x;
    r1 = up ? x : w;
#endif
}
// Split a 32-replicated value into its two 16-rows.
__device__ __forceinline__ void halfswap16(float x, float& r0, float& r1) {
#if __has_builtin(__builtin_amdgcn_permlane16_swap)
    auto r = __builtin_amdgcn_permlane16_swap(__float_as_int(x), __float_as_int(x), false, false);
    r0 = __int_as_float(r[0]); r1 = __int_as_float(r[1]);
#else
    float w = __int_as_float(__builtin_amdgcn_ds_swizzle(__float_as_int(x), 0x401F)); // xor16
    bool up = (threadIdx.x & 16) != 0;
    r0 = up ? w : x;
    r1 = up ? x : w;
#endif
}

__device__ __forceinline__ float wave_sum(float x) {
    x += dppf<0xB1>(x);   // quad_perm [1,0,3,2] : xor1
    x += dppf<0x4E>(x);   // quad_perm [2,3,0,1] : xor2
    x += dppf<0x141>(x);  // row_half_mirror     : xor7
    x += dppf<0x140>(x);  // row_mirror          : xor15  -> sum within 16
    float a, c;
    halfswap16(x, a, c); x = a + c;   // sum within 32 (convention-free)
    halfswap32(x, a, c); x = a + c;   // sum within 64
    return x;
}

// ---------------------------------------------------------------------------
// Kernel 1: out[0] = 0 (loss acc), out[1..4096] = transitions copy
// ---------------------------------------------------------------------------
__global__ __launch_bounds__(256) void crf_init_out(const float* __restrict__ trans,
                                                    float* __restrict__ out) {
    int idx = blockIdx.x * 256 + threadIdx.x;
    if (idx == 0) out[0] = 0.0f;
    if (idx < NC * NC) out[1 + idx] = trans[idx];
}

// ---------------------------------------------------------------------------
// Kernel 2: one wave per batch element, lane c owns class c.
// Linear-space forward: q'_c = (sum_i q_i * E[i][c]) * exp(x_c) / m
// with E = exp(T) in registers and an in-register 64-lane all-gather of q.
// ---------------------------------------------------------------------------
__global__ __launch_bounds__(64, 1) void crf_fwd(const float* __restrict__ inputs,
                                                 const int* __restrict__ masks,
                                                 const int* __restrict__ tags,
                                                 const float* __restrict__ trans,
                                                 float* __restrict__ out) {
    const int b = blockIdx.x;
    const int lane = threadIdx.x;

    __shared__ float Tlds[NC * NC];   // raw transitions for binary lookup
    __shared__ int   taglds[SL];

    const float* __restrict__ inrow = inputs + (size_t)b * SL * NC;

    // ---- stage transitions + tags; len via ballot (uniform, no LDS reduce)
#pragma unroll
    for (int i = 0; i < NC; ++i) Tlds[i * NC + lane] = trans[i * NC + lane];

    int len = 0;
#pragma unroll
    for (int k = 0; k < SL / NC; ++k) {
        int idx = k * NC + lane;
        taglds[idx] = tags[(size_t)b * SL + idx];
        unsigned long long bal = __ballot(masks[(size_t)b * SL + idx] == 0);
        len += __popcll(bal);
    }
    __syncthreads();

    // ---- probe: which 16-block does each gather family hold on THIS hw?
    int B[4];
    {
        float pf = __int_as_float(lane);
        float p0, p1, a0, a1, c0, c1;
        halfswap32(pf, p0, p1);
        halfswap16(p0, a0, a1);
        halfswap16(p1, c0, c1);
        B[0] = __builtin_amdgcn_readfirstlane(__float_as_int(a0));
        B[1] = __builtin_amdgcn_readfirstlane(__float_as_int(a1));
        B[2] = __builtin_amdgcn_readfirstlane(__float_as_int(c0));
        B[3] = __builtin_amdgcn_readfirstlane(__float_as_int(c1));
    }

    // ---- E registers matched to gather layout:
    // gather reg (f,m) holds q[B[f] + ((lane^m)&15)]  =>  E[f*16+m] = exp(T[that][lane])
    float E[64];
#pragma unroll
    for (int f = 0; f < 4; ++f) {
#pragma unroll
        for (int m = 0; m < 16; ++m) {
            int row = B[f] + ((lane ^ m) & 15);
            E[f * 16 + m] = __expf(Tlds[row * NC + lane]);
        }
    }

    // ---- t = 0 init
    float x0 = inrow[lane];
    float base = rflf(x0);
    float q = __expf(x0 - base);         // q[lane0] = 1
    int tagprev = taglds[0];
    float u = (lane == tagprev) ? x0 : 0.0f;
    float bacc = 0.0f;

    // software pipeline: x two ahead, exp(x) one ahead, tag one ahead
    int   tg_cur = taglds[1];
    float x_cur = inrow[NC + lane];       // row t=1
    float x_n1  = inrow[2 * NC + lane];   // row t=2 (len>=512 so always valid)
    float ex_cur = __expf(x_cur);

    for (int t = 1; t < len; ++t) {
        // --- off-chain: issue next loads / transcendentals early
        int t2 = t + 2; if (t2 > SL - 1) t2 = SL - 1;
        float x_n2 = inrow[(size_t)t2 * NC + lane];
        int tn = t + 1; if (tn > SL - 1) tn = SL - 1;
        int tg_next = taglds[tn];
        float Tv = Tlds[tagprev * NC + tg_cur];     // binary term (uniform)
        float ex_n1 = __expf(x_n1);

        // per-step rescale folded into the exp(x) factor (off-chain)
        float m  = rflf(q);
        float rm = __builtin_amdgcn_rcpf(m);
        float ex_eff = ex_cur * rm;
        base += __logf(m);

        // --- chain: all-to-all gather of q into 64 regs (VALU only)
        float v[64];
        {
            float u0, u1;
            halfswap32(q, u0, u1);
            halfswap16(u0, v[0],  v[16]);
            halfswap16(u1, v[32], v[48]);
#pragma unroll
            for (int F = 0; F < 64; F += 16) {
                v[F + 1]  = dppf<0xB1>(v[F + 0]);   // ^1
                v[F + 2]  = dppf<0x4E>(v[F + 0]);   // ^2
                v[F + 3]  = dppf<0x4E>(v[F + 1]);   // ^3
                v[F + 7]  = dppf<0x141>(v[F + 0]);  // ^7
                v[F + 6]  = dppf<0x141>(v[F + 1]);  // ^6
                v[F + 5]  = dppf<0x141>(v[F + 2]);  // ^5
                v[F + 4]  = dppf<0x141>(v[F + 3]);  // ^4
                v[F + 15] = dppf<0x140>(v[F + 0]);  // ^15
                v[F + 14] = dppf<0x140>(v[F + 1]);  // ^14
                v[F + 13] = dppf<0x140>(v[F + 2]);  // ^13
                v[F + 12] = dppf<0x140>(v[F + 3]);  // ^12
                v[F + 11] = dppf<0x140>(v[F + 4]);  // ^11
                v[F + 10] = dppf<0x140>(v[F + 5]);  // ^10
                v[F + 9]  = dppf<0x140>(v[F + 6]);  // ^9
                v[F + 8]  = dppf<0x140>(v[F + 7]);  // ^8
            }
        }

        // --- chain: matvec row, 8 accumulators
        float acc0 = 0.f, acc1 = 0.f, acc2 = 0.f, acc3 = 0.f;
        float acc4 = 0.f, acc5 = 0.f, acc6 = 0.f, acc7 = 0.f;
#pragma unroll
        for (int j = 0; j < 64; j += 8) {
            acc0 = fmaf(v[j + 0], E[j + 0], acc0);
            acc1 = fmaf(v[j + 1], E[j + 1], acc1);
            acc2 = fmaf(v[j + 2], E[j + 2], acc2);
            acc3 = fmaf(v[j + 3], E[j + 3], acc3);
            acc4 = fmaf(v[j + 4], E[j + 4], acc4);
            acc5 = fmaf(v[j + 5], E[j + 5], acc5);
            acc6 = fmaf(v[j + 6], E[j + 6], acc6);
            acc7 = fmaf(v[j + 7], E[j + 7], acc7);
        }
        float s = ((acc0 + acc1) + (acc2 + acc3)) + ((acc4 + acc5) + (acc6 + acc7));

        // --- off-chain: unary/binary accumulation
        u += (lane == tg_cur) ? x_cur : 0.0f;
        bacc += Tv;

        // --- chain tail
        q = s * ex_eff;

        // rotate pipeline
        tagprev = tg_cur; tg_cur = tg_next;
        x_cur = x_n1; x_n1 = x_n2; ex_cur = ex_n1;
    }

    // ---- epilogue: log_norm = base + log(sum_c q_c); reduce u across lanes
    float qsum = wave_sum(q);
    float usum = wave_sum(u);
    float log_norm = base + __logf(qsum);

    if (lane == 0) {
        float ll = usum + bacc - log_norm;
        atomicAdd(out, -ll * (1.0f / BS));
    }
}

// ---------------------------------------------------------------------------
extern "C" void kernel_launch(void* const* d_in, const int* in_sizes, int n_in,
                              void* d_out, int out_size, void* d_ws, size_t ws_size,
                              hipStream_t stream) {
    const float* inputs = (const float*)d_in[0];
    const int*   masks  = (const int*)d_in[1];
    const int*   tags   = (const int*)d_in[2];
    const float* trans  = (const float*)d_in[3];
    float* out = (float*)d_out;

    crf_init_out<<<(1 + NC * NC + 255) / 256, 256, 0, stream>>>(trans, out);
    crf_fwd<<<BS, 64, 0, stream>>>(inputs, masks, tags, trans, out);
}